// Round 11
// baseline (246.887 us; speedup 1.0000x reference)
//
#include <hip/hip_runtime.h>
#include <stdint.h>

#define T_ROWS 8192
#define IN_F 4096
#define OUT_F 4096

using i32x4 = __attribute__((ext_vector_type(4))) int;

#define GLOBAL_AS __attribute__((address_space(1)))
#define LDS_AS __attribute__((address_space(3)))

static __device__ __forceinline__ void load_lds16(const void* g, void* l) {
    __builtin_amdgcn_global_load_lds((const GLOBAL_AS uint32_t*)g,
                                     (LDS_AS uint32_t*)l, 16, 0, 0);
}

// -------- Kernel 1: fused prep: per-row int8 quant (blocks 0..8191) +
//                    ternary f32 -> int8 weight pack (blocks 8192..12287) --------
__global__ __launch_bounds__(256) void prep_kernel(const float* __restrict__ x,
                                                   int8_t* __restrict__ xq,
                                                   float* __restrict__ scales,
                                                   const float* __restrict__ w,
                                                   int8_t* __restrict__ w8) {
    if (blockIdx.x < T_ROWS) {
        const int row = blockIdx.x;
        const float* xr = x + (size_t)row * IN_F;
        const float4* xr4 = (const float4*)xr;

        float4 v[4];
        float amax = 0.0f;
#pragma unroll
        for (int i = 0; i < 4; ++i) {
            v[i] = xr4[threadIdx.x + 256 * i];
            amax = fmaxf(amax, fmaxf(fmaxf(fabsf(v[i].x), fabsf(v[i].y)),
                                     fmaxf(fabsf(v[i].z), fabsf(v[i].w))));
        }
#pragma unroll
        for (int off = 32; off; off >>= 1)
            amax = fmaxf(amax, __shfl_xor(amax, off, 64));
        __shared__ float smax[4];
        if ((threadIdx.x & 63) == 0) smax[threadIdx.x >> 6] = amax;
        __syncthreads();
        amax = fmaxf(fmaxf(smax[0], smax[1]), fmaxf(smax[2], smax[3]));

        const float act_scale = fmaxf(amax, 1e-10f) / 127.0f;
        if (threadIdx.x == 0) scales[row] = act_scale;

        int* xqr = (int*)(xq + (size_t)row * IN_F);
#pragma unroll
        for (int i = 0; i < 4; ++i) {
            int q0 = (int)fminf(fmaxf(rintf(v[i].x / act_scale), -127.0f), 127.0f);
            int q1 = (int)fminf(fmaxf(rintf(v[i].y / act_scale), -127.0f), 127.0f);
            int q2 = (int)fminf(fmaxf(rintf(v[i].z / act_scale), -127.0f), 127.0f);
            int q3 = (int)fminf(fmaxf(rintf(v[i].w / act_scale), -127.0f), 127.0f);
            int packed = (q0 & 0xff) | ((q1 & 0xff) << 8) | ((q2 & 0xff) << 16) | (q3 << 24);
            xqr[threadIdx.x + 256 * i] = packed;
        }
    } else {
        const float4* w4 = (const float4*)w;
        int* o4 = (int*)w8;
        size_t base = (size_t)(blockIdx.x - T_ROWS) * 1024 + threadIdx.x;
#pragma unroll
        for (int i = 0; i < 4; ++i) {
            size_t idx = base + 256 * i;
            float4 v = w4[idx];
            int q0 = (int)v.x, q1 = (int)v.y, q2 = (int)v.z, q3 = (int)v.w;
            o4[idx] = (q0 & 0xff) | ((q1 & 0xff) << 8) | ((q2 & 0xff) << 16) | (q3 << 24);
        }
    }
}

// -------- Kernel 2: m97-style 128x128 int8 MFMA GEMM, 2 blocks/CU --------
// C[t][o] = sum_k xq[t][k] * w8[o][k]   (NT: both row-major, K contiguous)
// 256 threads = 4 waves (2M x 2N). Per-wave output 64x64:
//   rows = wr*64 + m*16 (m=0..3), cols = wc*64 + n*16 (n=0..3).
// LDS: A,B each [buf 2][row 128][128B] = 32 KiB -> 64 KiB total => TWO blocks
// co-resident per CU with INDEPENDENT barriers. This is the m97/m114 overlap
// mechanism: when one block's waves drain at its pre-barrier vmcnt(0), the
// other block's waves keep issuing MFMA (measured 80% combined util at m97).
// All rounds 5-10 showed ~zero overlap WITHIN a barrier-synced block; this
// structure gets the overlap across blocks instead, for free.
// Layout/swizzle identical to the proven-conflict-free r6 scheme:
// slot s of row r at s^(r&7); gload_lds linear dest + pre-swizzled source;
// fragment reads pA = (row)*128 + ((lq^(l16&7))<<4), ks=1 via slot^4.
// K-loop (BK=128, 32 iters), NO inline asm -- compiler schedules waitcnts:
//   stage(buf^1, kt+1) issued first; 16 ds_read_b128 from buf; 32 MFMA;
//   __syncthreads() (compiler emits vmcnt(0)+lgkmcnt(0) drain before barrier,
//   which doubles as the RAW fence for next iter's reads of buf^1 and the
//   WAR fence for next iter's restage of buf).
// XCD column slabs: each XCD owns 4 col-tiles (512 cols = 2 MB of w8,
// L2-resident); rows sweep within the slab.
__global__ __launch_bounds__(256, 2) void gemm_kernel(const int8_t* __restrict__ xq,
                                                      const int8_t* __restrict__ w8,
                                                      const float* __restrict__ scales,
                                                      const float* __restrict__ bias,
                                                      const float* __restrict__ wscale_p,
                                                      float* __restrict__ out) {
    __shared__ __align__(16) int8_t As[2 * 128 * 128];  // 32 KiB
    __shared__ __align__(16) int8_t Bs[2 * 128 * 128];  // 32 KiB

    const int tid = threadIdx.x;
    const int lane = tid & 63;
    const int w = tid >> 6;     // wave 0..3
    const int wr = w >> 1;      // 0..1
    const int wc = w & 1;       // 0..1
    const int l16 = lane & 15;
    const int lq = lane >> 4;   // 0..3

    // XCD column-slab swizzle: grid 2048 = 64 row-tiles x 32 col-tiles.
    // xcd = orig&7 owns col-tiles {4*xcd .. 4*xcd+3}; rows sweep inside.
    const int orig = blockIdx.x;
    const int xcd = orig & 7;
    const int j = orig >> 3;                    // 0..255
    const int brow = (j >> 2) * 128;            // 64 row tiles
    const int bcol = (xcd * 4 + (j & 3)) * 128; // 32 col tiles

    // per-lane staging source: row +(lane>>3), K-slot (lane&7)^(lane>>3)
    const int lrow = lane >> 3;
    const int lslot = (lane & 7) ^ lrow;
    const int8_t* srcA = xq + (size_t)(brow + lrow) * IN_F + lslot * 16;
    const int8_t* srcB = w8 + (size_t)(bcol + lrow) * IN_F + lslot * 16;

    // per-lane fragment read pointers (ks=0 / ks=1 slots differ by ^4)
    const int sA = l16 & 7;
    const int8_t* pA0 = As + (wr * 64 + l16) * 128 + ((lq ^ sA) << 4);
    const int8_t* pA1 = As + (wr * 64 + l16) * 128 + (((lq ^ sA) ^ 4) << 4);
    const int8_t* pB0 = Bs + (wc * 64 + l16) * 128 + ((lq ^ sA) << 4);
    const int8_t* pB1 = Bs + (wc * 64 + l16) * 128 + (((lq ^ sA) ^ 4) << 4);

    // Stage one matrix tile (128 rows x 128B) for K-tile KT into buffer BUF.
    // 16 regions of 8 rows; wave w covers regions {w, w+4, w+8, w+12}.
#define STAGE(LDSA, SRC, BUF, KT) do {                                             \
    _Pragma("unroll") for (int i = 0; i < 4; ++i)                                  \
        load_lds16((SRC) + (size_t)((w + 4 * i) * 8) * IN_F + (KT) * 128,          \
                   (void*)((LDSA) + (BUF) * 16384 + (w + 4 * i) * 1024));          \
} while (0)

    i32x4 acc[4][4] = {};

    // Prologue: buf0 <- K-tile 0.
    STAGE(As, srcA, 0, 0);
    STAGE(Bs, srcB, 0, 0);
    __syncthreads();

    for (int kt = 0; kt < 32; ++kt) {
        const int buf = kt & 1;
        if (kt < 31) {
            STAGE(As, srcA, buf ^ 1, kt + 1);
            STAGE(Bs, srcB, buf ^ 1, kt + 1);
        }
        i32x4 a[4][2], b[4][2];
#pragma unroll
        for (int m = 0; m < 4; ++m) {
            a[m][0] = *(const i32x4*)(pA0 + buf * 16384 + m * 2048);
            a[m][1] = *(const i32x4*)(pA1 + buf * 16384 + m * 2048);
        }
#pragma unroll
        for (int n = 0; n < 4; ++n) {
            b[n][0] = *(const i32x4*)(pB0 + buf * 16384 + n * 2048);
            b[n][1] = *(const i32x4*)(pB1 + buf * 16384 + n * 2048);
        }
#pragma unroll
        for (int m = 0; m < 4; ++m)
#pragma unroll
            for (int n = 0; n < 4; ++n) {
                acc[m][n] = __builtin_amdgcn_mfma_i32_16x16x64_i8(a[m][0], b[n][0],
                                                                  acc[m][n], 0, 0, 0);
                acc[m][n] = __builtin_amdgcn_mfma_i32_16x16x64_i8(a[m][1], b[n][1],
                                                                  acc[m][n], 0, 0, 0);
            }
        __syncthreads();
    }

    // Epilogue: D mapping col = lane&15, row = lq*4 + j within each 16x16 frag.
    const float ws = wscale_p[0];
#pragma unroll
    for (int m = 0; m < 4; ++m) {
        const int row0 = brow + wr * 64 + m * 16 + lq * 4;
#pragma unroll
        for (int jj = 0; jj < 4; ++jj) {
            const int row = row0 + jj;
            const float sc = scales[row] * ws;
#pragma unroll
            for (int n = 0; n < 4; ++n) {
                const int col = bcol + wc * 64 + n * 16 + l16;
                out[(size_t)row * OUT_F + col] = (float)acc[m][n][jj] * sc + bias[col];
            }
        }
    }
#undef STAGE
}

extern "C" void kernel_launch(void* const* d_in, const int* in_sizes, int n_in,
                              void* d_out, int out_size, void* d_ws, size_t ws_size,
                              hipStream_t stream) {
    const float* x       = (const float*)d_in[0];
    const float* w_t     = (const float*)d_in[1];
    const float* w_scale = (const float*)d_in[2];
    const float* bias    = (const float*)d_in[3];
    float* out = (float*)d_out;

    int8_t* xq     = (int8_t*)d_ws;
    float*  scales = (float*)((char*)d_ws + (size_t)T_ROWS * IN_F);
    int8_t* w8     = (int8_t*)((char*)d_ws + (size_t)T_ROWS * IN_F + T_ROWS * sizeof(float));

    prep_kernel<<<T_ROWS + (OUT_F * IN_F) / (16 * 256), 256, 0, stream>>>(
        x, xq, scales, w_t, w8);

    gemm_kernel<<<(T_ROWS / 128) * (OUT_F / 128), 256, 0, stream>>>(
        xq, w8, scales, bias, w_scale, out);
}

// Round 12
// 178.848 us; speedup vs baseline: 1.3804x; 1.3804x over previous
//
#include <hip/hip_runtime.h>
#include <stdint.h>

#define T_ROWS 8192
#define IN_F 4096
#define OUT_F 4096

using i32x4 = __attribute__((ext_vector_type(4))) int;

#define GLOBAL_AS __attribute__((address_space(1)))
#define LDS_AS __attribute__((address_space(3)))

static __device__ __forceinline__ void load_lds16(const void* g, void* l) {
    __builtin_amdgcn_global_load_lds((const GLOBAL_AS uint32_t*)g,
                                     (LDS_AS uint32_t*)l, 16, 0, 0);
}

// -------- Kernel 1: fused prep: per-row int8 quant (blocks 0..8191) +
//                    ternary f32 -> int8 weight pack (blocks 8192..12287) --------
// At the HBM floor: 240 MB moved in ~40 us (~6 TB/s).
__global__ __launch_bounds__(256) void prep_kernel(const float* __restrict__ x,
                                                   int8_t* __restrict__ xq,
                                                   float* __restrict__ scales,
                                                   const float* __restrict__ w,
                                                   int8_t* __restrict__ w8) {
    if (blockIdx.x < T_ROWS) {
        const int row = blockIdx.x;
        const float* xr = x + (size_t)row * IN_F;
        const float4* xr4 = (const float4*)xr;

        float4 v[4];
        float amax = 0.0f;
#pragma unroll
        for (int i = 0; i < 4; ++i) {
            v[i] = xr4[threadIdx.x + 256 * i];
            amax = fmaxf(amax, fmaxf(fmaxf(fabsf(v[i].x), fabsf(v[i].y)),
                                     fmaxf(fabsf(v[i].z), fabsf(v[i].w))));
        }
#pragma unroll
        for (int off = 32; off; off >>= 1)
            amax = fmaxf(amax, __shfl_xor(amax, off, 64));
        __shared__ float smax[4];
        if ((threadIdx.x & 63) == 0) smax[threadIdx.x >> 6] = amax;
        __syncthreads();
        amax = fmaxf(fmaxf(smax[0], smax[1]), fmaxf(smax[2], smax[3]));

        const float act_scale = fmaxf(amax, 1e-10f) / 127.0f;
        if (threadIdx.x == 0) scales[row] = act_scale;

        int* xqr = (int*)(xq + (size_t)row * IN_F);
#pragma unroll
        for (int i = 0; i < 4; ++i) {
            int q0 = (int)fminf(fmaxf(rintf(v[i].x / act_scale), -127.0f), 127.0f);
            int q1 = (int)fminf(fmaxf(rintf(v[i].y / act_scale), -127.0f), 127.0f);
            int q2 = (int)fminf(fmaxf(rintf(v[i].z / act_scale), -127.0f), 127.0f);
            int q3 = (int)fminf(fmaxf(rintf(v[i].w / act_scale), -127.0f), 127.0f);
            int packed = (q0 & 0xff) | ((q1 & 0xff) << 8) | ((q2 & 0xff) << 16) | (q3 << 24);
            xqr[threadIdx.x + 256 * i] = packed;
        }
    } else {
        const float4* w4 = (const float4*)w;
        int* o4 = (int*)w8;
        size_t base = (size_t)(blockIdx.x - T_ROWS) * 1024 + threadIdx.x;
#pragma unroll
        for (int i = 0; i < 4; ++i) {
            size_t idx = base + 256 * i;
            float4 v = w4[idx];
            int q0 = (int)v.x, q1 = (int)v.y, q2 = (int)v.z, q3 = (int)v.w;
            o4[idx] = (q0 & 0xff) | ((q1 & 0xff) << 8) | ((q2 & 0xff) << 16) | (q3 << 24);
        }
    }
}

// ---------------- Kernel 2: 256x256 8-phase int8 MFMA GEMM (r6, best) ----------
// C[t][o] = sum_k xq[t][k] * w8[o][k]   (NT: both row-major, K contiguous)
// 512 threads = 8 waves (2M x 4N). Per-wave output 128x64 interleaved:
//   rows = m*32 + wr*16 (m=0..7), cols = n*64 + wc*16 (n=0..3).
// LDS: row-major [buf 2][row 256][128B] per matrix (32 KB/buf), XOR-swizzled:
//   16B slot s of row r lives at slot s ^ (r&7). Total 128 KiB.
// Staging: linear LDS dest via global_load_lds (8 rows x 128B contiguous per
// instr => ideal coalescing) with per-lane pre-swizzled global source
// (rule #21 both-sides). Measured conflict-free.
// Snake quadrant order per buffer with register-persistent fragments
// (reads/phase 12/4/8/0, B issued before A); one trailing barrier per phase;
// vmcnt(6) at p4/p8 retires exactly the next buffer's 8 loads.
// Measured (rounds 6/9): 132 us GEMM, MfmaUtil 44%, conflicts 0 -- 98% of the
// serial-sum floor (LDS-read 2304 + LDS-write 512 + MFMA 2046 cyc per
// K-tile/CU). Seven structural variants (barrier thinning, explicit
// register pipelining with sched_barrier pinning, m201-exact phase shape,
// B-direct-from-L2, 128^2 tile with 2 blocks/CU) all landed 4-55% worse:
// on this op the per-CU LDS unit serializes with MFMA regardless of
// schedule, so minimizing LDS bytes (this structure) is optimal.
__global__ __launch_bounds__(512, 2) void gemm_kernel(const int8_t* __restrict__ xq,
                                                      const int8_t* __restrict__ w8,
                                                      const float* __restrict__ scales,
                                                      const float* __restrict__ bias,
                                                      const float* __restrict__ wscale_p,
                                                      float* __restrict__ out) {
    __shared__ __align__(16) int8_t As[2 * 256 * 128];  // 64 KiB
    __shared__ __align__(16) int8_t Bs[2 * 256 * 128];  // 64 KiB

    const int tid = threadIdx.x;
    const int lane = tid & 63;
    const int w = tid >> 6;     // wave 0..7
    const int wr = w >> 2;      // 0..1
    const int wc = w & 3;       // 0..3
    const int l16 = lane & 15;
    const int lq = lane >> 4;   // 0..3

    // XCD-aware swizzle: nwg=512 (divisible by 8), contiguous chunk of 64 per XCD.
    int bid = blockIdx.x;
    bid = (bid & 7) * 64 + (bid >> 3);
    const int brow = (bid >> 4) * 256;
    const int bcol = (bid & 15) * 256;

    // per-lane staging source: row +(lane>>3), K-slot (lane&7)^(lane>>3)
    const int lrow = lane >> 3;
    const int lslot = (lane & 7) ^ lrow;
    const int8_t* srcA = xq + (size_t)(brow + lrow) * IN_F + lslot * 16;
    const int8_t* srcB = w8 + (size_t)(bcol + lrow) * IN_F + lslot * 16;

    // per-lane fragment read pointers (ks=0 / ks=1 slots differ by ^4)
    const int sA = l16 & 7;
    const int8_t* pA0 = As + (wr * 16 + l16) * 128 + ((lq ^ sA) << 4);
    const int8_t* pA1 = As + (wr * 16 + l16) * 128 + (((lq ^ sA) ^ 4) << 4);
    const int8_t* pB0 = Bs + (wc * 16 + l16) * 128 + ((lq ^ sA) << 4);
    const int8_t* pB1 = Bs + (wc * 16 + l16) * 128 + (((lq ^ sA) ^ 4) << 4);

// Stage one half-tile (128 rows x 128B) of matrix LDSA from SRC, K-tile KT,
// into buffer BUF. Wave w covers 8-row regions {w, w+8} of the half.
#define STAGE(LDSA, SRC, BUF, H, KT) do {                                          \
    load_lds16((SRC) + (size_t)((H) * 128 + w * 8) * IN_F + (KT) * 128,            \
               (void*)((LDSA) + (BUF) * 32768 + ((H) * 16 + w) * 1024));           \
    load_lds16((SRC) + (size_t)((H) * 128 + (w + 8) * 8) * IN_F + (KT) * 128,      \
               (void*)((LDSA) + (BUF) * 32768 + ((H) * 16 + w + 8) * 1024));       \
} while (0)

#define READ_A(BUF, MH)                                                            \
    _Pragma("unroll") for (int m = 0; m < 4; ++m) {                                \
        ra[m][0] = *(const i32x4*)(pA0 + (BUF) * 32768 + ((MH) * 4 + m) * 4096);   \
        ra[m][1] = *(const i32x4*)(pA1 + (BUF) * 32768 + ((MH) * 4 + m) * 4096);   \
    }

#define READ_B(BUF, NH, RB)                                                        \
    _Pragma("unroll") for (int n = 0; n < 2; ++n) {                                \
        RB[n][0] = *(const i32x4*)(pB0 + (BUF) * 32768 + ((NH) * 2 + n) * 8192);   \
        RB[n][1] = *(const i32x4*)(pB1 + (BUF) * 32768 + ((NH) * 2 + n) * 8192);   \
    }

#define PHASE(READS, STAGE_STMT, MH, NH, RB, VM_STMT) do {                         \
    READS;                                                                         \
    STAGE_STMT;                                                                    \
    __builtin_amdgcn_s_setprio(1);                                                 \
    _Pragma("unroll") for (int m = 0; m < 4; ++m)                                  \
    _Pragma("unroll") for (int n = 0; n < 2; ++n) {                                \
        acc[(MH) * 4 + m][(NH) * 2 + n] = __builtin_amdgcn_mfma_i32_16x16x64_i8(   \
            ra[m][0], RB[n][0], acc[(MH) * 4 + m][(NH) * 2 + n], 0, 0, 0);         \
        acc[(MH) * 4 + m][(NH) * 2 + n] = __builtin_amdgcn_mfma_i32_16x16x64_i8(   \
            ra[m][1], RB[n][1], acc[(MH) * 4 + m][(NH) * 2 + n], 0, 0, 0);         \
    }                                                                              \
    __builtin_amdgcn_s_setprio(0);                                                 \
    VM_STMT;                                                                       \
    __builtin_amdgcn_s_barrier();                                                  \
    asm volatile("" ::: "memory");                                                 \
} while (0)

    i32x4 acc[8][4] = {};
    i32x4 ra[4][2], rb0[2][2], rb1[2][2];

    // Prologue: buf0 <- K-tile 0 (4 halves), buf1 <- K-tile 1 (A0, B0, B1).
    STAGE(As, srcA, 0, 0, 0);
    STAGE(Bs, srcB, 0, 0, 0);
    STAGE(Bs, srcB, 0, 1, 0);
    STAGE(As, srcA, 0, 1, 0);
    STAGE(As, srcA, 1, 0, 1);
    STAGE(Bs, srcB, 1, 0, 1);
    STAGE(Bs, srcB, 1, 1, 1);
    asm volatile("s_waitcnt vmcnt(6)" ::: "memory");  // buf0's 8 loads done
    __builtin_amdgcn_s_barrier();
    asm volatile("" ::: "memory");

    for (int t = 0; t < 16; ++t) {
        const int k1 = 2 * t + 1;
        const int k2 = (2 * t + 2) & 31;  // wrap on last iter: dead-but-safe stages
        const int k3 = (2 * t + 3) & 31;
        PHASE(READ_B(0, 0, rb0); READ_A(0, 0), STAGE(As, srcA, 1, 1, k1), 0, 0, rb0, );
        PHASE(READ_B(0, 1, rb1),               STAGE(As, srcA, 0, 0, k2), 0, 1, rb1, );
        PHASE(READ_A(0, 1),                    STAGE(Bs, srcB, 0, 0, k2), 1, 1, rb1, );
        PHASE(,                                STAGE(Bs, srcB, 0, 1, k2), 1, 0, rb0,
              asm volatile("s_waitcnt vmcnt(6)" ::: "memory"));
        PHASE(READ_B(1, 0, rb0); READ_A(1, 0), STAGE(As, srcA, 0, 1, k2), 0, 0, rb0, );
        PHASE(READ_B(1, 1, rb1),               STAGE(As, srcA, 1, 0, k3), 0, 1, rb1, );
        PHASE(READ_A(1, 1),                    STAGE(Bs, srcB, 1, 0, k3), 1, 1, rb1, );
        PHASE(,                                STAGE(Bs, srcB, 1, 1, k3), 1, 0, rb0,
              asm volatile("s_waitcnt vmcnt(6)" ::: "memory"));
    }

    // Epilogue: D mapping col = lane&15, row = lq*4 + j within each 16x16 frag.
    const float ws = wscale_p[0];
#pragma unroll
    for (int m = 0; m < 8; ++m) {
        const int row0 = brow + m * 32 + wr * 16 + lq * 4;
#pragma unroll
        for (int j = 0; j < 4; ++j) {
            const int row = row0 + j;
            const float sc = scales[row] * ws;
#pragma unroll
            for (int n = 0; n < 4; ++n) {
                const int col = bcol + n * 64 + wc * 16 + l16;
                out[(size_t)row * OUT_F + col] = (float)acc[m][n][j] * sc + bias[col];
            }
        }
    }
#undef STAGE
#undef READ_A
#undef READ_B
#undef PHASE
}

extern "C" void kernel_launch(void* const* d_in, const int* in_sizes, int n_in,
                              void* d_out, int out_size, void* d_ws, size_t ws_size,
                              hipStream_t stream) {
    const float* x       = (const float*)d_in[0];
    const float* w_t     = (const float*)d_in[1];
    const float* w_scale = (const float*)d_in[2];
    const float* bias    = (const float*)d_in[3];
    float* out = (float*)d_out;

    int8_t* xq     = (int8_t*)d_ws;
    float*  scales = (float*)((char*)d_ws + (size_t)T_ROWS * IN_F);
    int8_t* w8     = (int8_t*)((char*)d_ws + (size_t)T_ROWS * IN_F + T_ROWS * sizeof(float));

    prep_kernel<<<T_ROWS + (OUT_F * IN_F) / (16 * 256), 256, 0, stream>>>(
        x, xq, scales, w_t, w8);

    gemm_kernel<<<(T_ROWS / 256) * (OUT_F / 256), 512, 0, stream>>>(
        xq, w8, scales, bias, w_scale, out);
}